// Round 3
// baseline (466.977 us; speedup 1.0000x reference)
//
#include <hip/hip_runtime.h>
#include <hip/hip_bf16.h>
#include <stdint.h>

#define N_PTS   4096
#define M_CODES 4096
#define ZDIM    1024
#define BM 128
#define BN 128
#define BK 32
#define GRID    ((N_PTS / BM) * (M_CODES / BN))   // 1024

typedef __attribute__((ext_vector_type(8))) short bf16x8;
typedef __attribute__((ext_vector_type(4))) float f32x4;

__device__ __forceinline__ unsigned short f2bf(float f) {
    __hip_bfloat16 h = __float2bfloat16(f);
    return *reinterpret_cast<unsigned short*>(&h);
}

// order-preserving float -> uint map (monotone): enables atomicMin on uint
__device__ __forceinline__ unsigned enc_f32(float f) {
    unsigned u = __float_as_uint(f);
    return (u & 0x80000000u) ? ~u : (u | 0x80000000u);
}
__device__ __forceinline__ float dec_f32(unsigned e) {
    unsigned u = (e & 0x80000000u) ? (e ^ 0x80000000u) : ~e;
    return __uint_as_float(u);
}

// ---------------------------------------------------------------------------
// Single fused kernel:
//   Phase 1: fp32->bf16 convert of z,e (8 rows/block) + row sum-of-squares.
//            zsq -> global array; esq row sums -> one float atomicAdd (only
//            the SUM over codes is needed: min_i(dist) = min_i(zsq-2c) + esq).
//   Grid barrier (all 1024 blocks co-resident: __launch_bounds__(256,4)
//            caps VGPR at 128 -> >=4 blocks/CU -> capacity >= GRID).
//   Phase 2: R1-proven 128x128x32 bf16 MFMA GEMM (lane-contiguous
//            global_load_lds staging), fused column-min epilogue,
//            last-done block computes the scalar mean.
// ---------------------------------------------------------------------------
__global__ __launch_bounds__(256, 4) void fused_kernel(
    const float* __restrict__ z, const float* __restrict__ e,
    unsigned short* __restrict__ zb, unsigned short* __restrict__ eb,
    float* __restrict__ zsq, unsigned* __restrict__ min_enc,
    unsigned* __restrict__ ctrl,  // [0]=barrier, [1]=done, [2]=esq_total bits
    float* __restrict__ out) {
    __shared__ __align__(16) unsigned short As[BM * BK];  // 8 KB
    __shared__ __align__(16) unsigned short Bs[BN * BK];  // 8 KB
    __shared__ float zsq_s[BM];
    __shared__ float colmin[2][BN];
    __shared__ float red[4];
    __shared__ int last_flag;

    const int t = threadIdx.x;
    const int b = blockIdx.x;
    const int lane = t & 63;
    const int w = t >> 6;

    // ---------------- Phase 1: convert + row sums ----------------
    #pragma unroll
    for (int r = 0; r < 2; r++) {
        const int row = b * 8 + w * 2 + r;  // 0..8191
        const bool is_z = row < N_PTS;
        const int rr = is_z ? row : row - N_PTS;
        const float* src = (is_z ? z : e) + (size_t)rr * ZDIM;
        unsigned short* dst = (is_z ? zb : eb) + (size_t)rr * ZDIM;
        const float4* s4 = reinterpret_cast<const float4*>(src);
        ushort4* d4 = reinterpret_cast<ushort4*>(dst);
        float s = 0.f;
        #pragma unroll
        for (int i = 0; i < 4; i++) {
            float4 v = s4[i * 64 + lane];
            ushort4 o;
            o.x = f2bf(v.x); o.y = f2bf(v.y); o.z = f2bf(v.z); o.w = f2bf(v.w);
            d4[i * 64 + lane] = o;
            s += v.x * v.x + v.y * v.y + v.z * v.z + v.w * v.w;
        }
        #pragma unroll
        for (int off = 1; off < 64; off <<= 1) s += __shfl_xor(s, off, 64);
        if (lane == 0) {
            if (is_z) zsq[rr] = s;
            else atomicAdd((float*)&ctrl[2], s);  // device-scope f32 atomic
        }
    }

    // ---------------- Grid barrier (release -> arrive -> spin -> acquire) ---
    __threadfence();   // release: flush this block's writes toward coherent pt
    __syncthreads();
    if (t == 0) {
        __hip_atomic_fetch_add(&ctrl[0], 1u, __ATOMIC_ACQ_REL,
                               __HIP_MEMORY_SCOPE_AGENT);
        while (__hip_atomic_load(&ctrl[0], __ATOMIC_ACQUIRE,
                                 __HIP_MEMORY_SCOPE_AGENT) < (unsigned)GRID)
            __builtin_amdgcn_s_sleep(8);
    }
    __syncthreads();
    __threadfence();   // acquire: invalidate stale L1/L2 lines (buffer_inv)

    // ---------------- Phase 2: GEMM + fused min ----------------
    const int bx = b & 31;   // code (col) block
    const int by = b >> 5;   // point (row) block
    const int wm = w >> 1, wn = w & 1;
    const int lrow = lane & 15;
    const int q = lane >> 4;

    if (t < BM) zsq_s[t] = zsq[by * BM + t];

    f32x4 acc[4][4];
    #pragma unroll
    for (int i = 0; i < 4; i++)
        #pragma unroll
        for (int j = 0; j < 4; j++) acc[i][j] = (f32x4){0.f, 0.f, 0.f, 0.f};

    // staging geometry (R1-proven, lane-contiguous source AND dest):
    // thread t covers bytes [t*16, t*16+16) of the 8 KB tile (instr 0),
    // and the same +4096 B (instr 1). Tile row = 64 B.
    const int row0 = (t * 16) >> 6;         // 0..63
    const int kel0 = ((t * 16) & 63) >> 1;  // k-element offset 0/8/16/24
    const int lds_b0 = w * 512;             // wave-uniform LDS base (elements)
    const size_t a_base = (size_t)(by * BM) * ZDIM;
    const size_t b_base = (size_t)(bx * BN) * ZDIM;

    for (int k0 = 0; k0 < ZDIM; k0 += BK) {
        const unsigned short* ga0 = zb + a_base + (size_t)row0 * ZDIM + k0 + kel0;
        const unsigned short* gb0 = eb + b_base + (size_t)row0 * ZDIM + k0 + kel0;
        __builtin_amdgcn_global_load_lds(
            (const __attribute__((address_space(1))) void*)ga0,
            (__attribute__((address_space(3))) void*)(As + lds_b0), 16, 0, 0);
        __builtin_amdgcn_global_load_lds(
            (const __attribute__((address_space(1))) void*)(ga0 + (size_t)64 * ZDIM),
            (__attribute__((address_space(3))) void*)(As + 2048 + lds_b0), 16, 0, 0);
        __builtin_amdgcn_global_load_lds(
            (const __attribute__((address_space(1))) void*)gb0,
            (__attribute__((address_space(3))) void*)(Bs + lds_b0), 16, 0, 0);
        __builtin_amdgcn_global_load_lds(
            (const __attribute__((address_space(1))) void*)(gb0 + (size_t)64 * ZDIM),
            (__attribute__((address_space(3))) void*)(Bs + 2048 + lds_b0), 16, 0, 0);
        __syncthreads();

        bf16x8 a[4], bb[4];
        #pragma unroll
        for (int am = 0; am < 4; am++)
            a[am] = *(const bf16x8*)(As + (wm * 64 + am * 16 + lrow) * BK + q * 8);
        #pragma unroll
        for (int an = 0; an < 4; an++)
            bb[an] = *(const bf16x8*)(Bs + (wn * 64 + an * 16 + lrow) * BK + q * 8);
        #pragma unroll
        for (int am = 0; am < 4; am++)
            #pragma unroll
            for (int an = 0; an < 4; an++)
                acc[am][an] = __builtin_amdgcn_mfma_f32_16x16x32_bf16(
                    a[am], bb[an], acc[am][an], 0, 0, 0);
        __syncthreads();
    }

    // Epilogue: per-lane min, cross-lane over q, LDS-combine the two wm
    // waves, one atomicMin per column per block.
    // C/D layout: row = q*4+r, col = lrow (m89-verified).
    #pragma unroll
    for (int an = 0; an < 4; an++) {
        float v = 3.4e38f;
        #pragma unroll
        for (int am = 0; am < 4; am++) {
            const int rbase = wm * 64 + am * 16 + q * 4;
            f32x4 c = acc[am][an];
            v = fminf(v, zsq_s[rbase + 0] - 2.f * c[0]);
            v = fminf(v, zsq_s[rbase + 1] - 2.f * c[1]);
            v = fminf(v, zsq_s[rbase + 2] - 2.f * c[2]);
            v = fminf(v, zsq_s[rbase + 3] - 2.f * c[3]);
        }
        v = fminf(v, __shfl_xor(v, 16, 64));
        v = fminf(v, __shfl_xor(v, 32, 64));
        if (q == 0) colmin[wm][wn * 64 + an * 16 + lrow] = v;
    }
    __syncthreads();
    if (t < BN) {
        const float m = fminf(colmin[0][t], colmin[1][t]);
        atomicMin(&min_enc[bx * BN + t], enc_f32(m));
    }

    // Fused finalize: last block reduces min_enc -> mean -> out.
    __threadfence();
    if (t == 0) {
        unsigned old = __hip_atomic_fetch_add(&ctrl[1], 1u, __ATOMIC_ACQ_REL,
                                              __HIP_MEMORY_SCOPE_AGENT);
        last_flag = (old == (unsigned)(GRID - 1));
    }
    __syncthreads();
    if (last_flag) {
        __threadfence();  // acquire
        float s = 0.f;
        #pragma unroll
        for (int i = 0; i < M_CODES / 256; i++) {
            const int j = i * 256 + t;
            unsigned enc = __hip_atomic_load(&min_enc[j], __ATOMIC_RELAXED,
                                             __HIP_MEMORY_SCOPE_AGENT);
            s += dec_f32(enc);
        }
        #pragma unroll
        for (int off = 1; off < 64; off <<= 1) s += __shfl_xor(s, off, 64);
        if (lane == 0) red[w] = s;
        __syncthreads();
        if (t == 0) {
            unsigned eb_bits = __hip_atomic_load(&ctrl[2], __ATOMIC_RELAXED,
                                                 __HIP_MEMORY_SCOPE_AGENT);
            float esq_total = __uint_as_float(eb_bits);
            out[0] = (red[0] + red[1] + red[2] + red[3] + esq_total)
                     * (1.f / M_CODES);
        }
    }
}

extern "C" void kernel_launch(void* const* d_in, const int* in_sizes, int n_in,
                              void* d_out, int out_size, void* d_ws, size_t ws_size,
                              hipStream_t stream) {
    (void)in_sizes; (void)n_in; (void)out_size; (void)ws_size;
    const float* z = (const float*)d_in[0];
    const float* e = (const float*)d_in[1];
    char* ws = (char*)d_ws;
    unsigned short* zb = (unsigned short*)ws;                            // 8 MB
    unsigned short* eb = (unsigned short*)(ws + ((size_t)8 << 20));      // 8 MB
    float* zsq = (float*)(ws + ((size_t)16 << 20));                      // 16 KB
    unsigned* min_enc = (unsigned*)(ws + ((size_t)16 << 20) + 16384);    // 16 KB
    unsigned* ctrl = (unsigned*)(ws + ((size_t)16 << 20) + 32768);       // 16 B

    hipMemsetAsync(min_enc, 0xFF, M_CODES * sizeof(unsigned), stream);
    hipMemsetAsync(ctrl, 0, 16, stream);
    fused_kernel<<<dim3(GRID), dim3(256), 0, stream>>>(
        z, e, zb, eb, zsq, min_enc, ctrl, (float*)d_out);
}

// Round 4
// 245.348 us; speedup vs baseline: 1.9033x; 1.9033x over previous
//
#include <hip/hip_runtime.h>
#include <hip/hip_bf16.h>
#include <stdint.h>

#define N_PTS   4096
#define M_CODES 4096
#define ZDIM    1024
#define BM 128
#define BN 128
#define BK 32
#define GRID_GEMM ((N_PTS / BM) * (M_CODES / BN))   // 1024

typedef __attribute__((ext_vector_type(8))) short bf16x8;
typedef __attribute__((ext_vector_type(4))) float f32x4;

__device__ __forceinline__ unsigned short f2bf(float f) {
    __hip_bfloat16 h = __float2bfloat16(f);
    return *reinterpret_cast<unsigned short*>(&h);
}

// order-preserving float -> uint map (monotone): enables atomicMin on uint
__device__ __forceinline__ unsigned enc_f32(float f) {
    unsigned u = __float_as_uint(f);
    return (u & 0x80000000u) ? ~u : (u | 0x80000000u);
}
__device__ __forceinline__ float dec_f32(unsigned e) {
    unsigned u = (e & 0x80000000u) ? (e ^ 0x80000000u) : ~e;
    return __uint_as_float(u);
}

// ---------------------------------------------------------------------------
// prep: fp32 -> bf16 convert + row sum-of-squares, high-ILP version.
// 1024 blocks x 256 threads; 8 rows/block (2 rows/wave), 8 float4 loads/lane
// in flight, no LDS, no __syncthreads. esq is only needed as a TOTAL
// (min_i dist = min_i(zsq_i - 2c_ij) + esq_j; mean adds sum(esq)/M), so e-row
// sums go into one float accumulator (ctrl[2]) via atomicAdd.
// Also initializes min_enc and the done-counter (no hipMemsetAsync needed).
// ---------------------------------------------------------------------------
__global__ __launch_bounds__(256) void prep_kernel(
    const float* __restrict__ z, const float* __restrict__ e,
    unsigned short* __restrict__ zb, unsigned short* __restrict__ eb,
    float* __restrict__ zsq, unsigned* __restrict__ min_enc,
    unsigned* __restrict__ ctrl) {
    const int t = threadIdx.x;
    const int b = blockIdx.x;
    if (b < 16) min_enc[b * 256 + t] = 0xFFFFFFFFu;  // encodes "+huge"
    if (b == 16 && t < 4) ctrl[t] = 0u;              // done ctr + esq bits

    const int w = t >> 6, lane = t & 63;
    const bool is_z = b < 512;  // block-uniform: rows 0..4095 are z, rest e
    #pragma unroll
    for (int r2 = 0; r2 < 2; r2++) {
        const int rr = (b & 511) * 8 + w * 2 + r2;  // row within z or e
        const float4* s4 =
            reinterpret_cast<const float4*>((is_z ? z : e) + (size_t)rr * ZDIM);
        ushort4* d4 =
            reinterpret_cast<ushort4*>((is_z ? zb : eb) + (size_t)rr * ZDIM);
        float4 v0 = s4[lane], v1 = s4[64 + lane], v2 = s4[128 + lane],
               v3 = s4[192 + lane];
        ushort4 o0, o1, o2, o3;
        o0.x = f2bf(v0.x); o0.y = f2bf(v0.y); o0.z = f2bf(v0.z); o0.w = f2bf(v0.w);
        o1.x = f2bf(v1.x); o1.y = f2bf(v1.y); o1.z = f2bf(v1.z); o1.w = f2bf(v1.w);
        o2.x = f2bf(v2.x); o2.y = f2bf(v2.y); o2.z = f2bf(v2.z); o2.w = f2bf(v2.w);
        o3.x = f2bf(v3.x); o3.y = f2bf(v3.y); o3.z = f2bf(v3.z); o3.w = f2bf(v3.w);
        d4[lane] = o0; d4[64 + lane] = o1; d4[128 + lane] = o2; d4[192 + lane] = o3;
        float s = v0.x * v0.x + v0.y * v0.y + v0.z * v0.z + v0.w * v0.w
                + v1.x * v1.x + v1.y * v1.y + v1.z * v1.z + v1.w * v1.w
                + v2.x * v2.x + v2.y * v2.y + v2.z * v2.z + v2.w * v2.w
                + v3.x * v3.x + v3.y * v3.y + v3.z * v3.z + v3.w * v3.w;
        #pragma unroll
        for (int off = 1; off < 64; off <<= 1) s += __shfl_xor(s, off, 64);
        if (lane == 0) {
            if (is_z) zsq[rr] = s;
            else atomicAdd((float*)&ctrl[2], s);
        }
    }
}

// ---------------------------------------------------------------------------
// gemm_min: EXACT R1 inner loop (proven 53 us): 128x128x32 bf16 MFMA,
// lane-contiguous global_load_lds staging. Epilogue: column-min, LDS-combine
// of the two wm waves (128 atomicMin/block), last-done block computes the
// scalar mean (validated in R2 — no grid barrier, no spin).
// grid = (32, 32), 256 threads = 4 waves (2x2 of 64x64).
// ---------------------------------------------------------------------------
__global__ __launch_bounds__(256) void gemm_min_kernel(
    const unsigned short* __restrict__ zb, const unsigned short* __restrict__ eb,
    const float* __restrict__ zsq, unsigned* __restrict__ min_enc,
    unsigned* __restrict__ ctrl, float* __restrict__ out) {
    __shared__ __align__(16) unsigned short As[BM * BK];  // 8 KB
    __shared__ __align__(16) unsigned short Bs[BN * BK];  // 8 KB
    __shared__ float zsq_s[BM];
    __shared__ float colmin[2][BN];
    __shared__ float red[4];
    __shared__ int last_flag;

    const int t = threadIdx.x;
    const int bx = blockIdx.x;  // code (col) block
    const int by = blockIdx.y;  // point (row) block
    const int lane = t & 63;
    const int w = t >> 6;
    const int wm = w >> 1, wn = w & 1;
    const int lrow = lane & 15;
    const int q = lane >> 4;

    if (t < BM) zsq_s[t] = zsq[by * BM + t];

    f32x4 acc[4][4];
    #pragma unroll
    for (int i = 0; i < 4; i++)
        #pragma unroll
        for (int j = 0; j < 4; j++) acc[i][j] = (f32x4){0.f, 0.f, 0.f, 0.f};

    // staging geometry (R1-proven, lane-contiguous source AND dest):
    // thread t covers bytes [t*16, t*16+16) of the 8 KB tile (instr 0),
    // and the same +4096 B (instr 1). Tile row = 64 B.
    const int row0 = (t * 16) >> 6;         // 0..63
    const int kel0 = ((t * 16) & 63) >> 1;  // k-element offset 0/8/16/24
    const int lds_b0 = w * 512;             // wave-uniform LDS base (elements)
    const size_t a_base = (size_t)(by * BM) * ZDIM;
    const size_t b_base = (size_t)(bx * BN) * ZDIM;

    for (int k0 = 0; k0 < ZDIM; k0 += BK) {
        const unsigned short* ga0 = zb + a_base + (size_t)row0 * ZDIM + k0 + kel0;
        const unsigned short* gb0 = eb + b_base + (size_t)row0 * ZDIM + k0 + kel0;
        __builtin_amdgcn_global_load_lds(
            (const __attribute__((address_space(1))) void*)ga0,
            (__attribute__((address_space(3))) void*)(As + lds_b0), 16, 0, 0);
        __builtin_amdgcn_global_load_lds(
            (const __attribute__((address_space(1))) void*)(ga0 + (size_t)64 * ZDIM),
            (__attribute__((address_space(3))) void*)(As + 2048 + lds_b0), 16, 0, 0);
        __builtin_amdgcn_global_load_lds(
            (const __attribute__((address_space(1))) void*)gb0,
            (__attribute__((address_space(3))) void*)(Bs + lds_b0), 16, 0, 0);
        __builtin_amdgcn_global_load_lds(
            (const __attribute__((address_space(1))) void*)(gb0 + (size_t)64 * ZDIM),
            (__attribute__((address_space(3))) void*)(Bs + 2048 + lds_b0), 16, 0, 0);
        __syncthreads();

        bf16x8 a[4], bb[4];
        #pragma unroll
        for (int am = 0; am < 4; am++)
            a[am] = *(const bf16x8*)(As + (wm * 64 + am * 16 + lrow) * BK + q * 8);
        #pragma unroll
        for (int an = 0; an < 4; an++)
            bb[an] = *(const bf16x8*)(Bs + (wn * 64 + an * 16 + lrow) * BK + q * 8);
        #pragma unroll
        for (int am = 0; am < 4; am++)
            #pragma unroll
            for (int an = 0; an < 4; an++)
                acc[am][an] = __builtin_amdgcn_mfma_f32_16x16x32_bf16(
                    a[am], bb[an], acc[am][an], 0, 0, 0);
        __syncthreads();
    }

    // Epilogue. C/D layout: row = q*4+r, col = lrow (m89-verified).
    #pragma unroll
    for (int an = 0; an < 4; an++) {
        float v = 3.4e38f;
        #pragma unroll
        for (int am = 0; am < 4; am++) {
            const int rbase = wm * 64 + am * 16 + q * 4;
            f32x4 c = acc[am][an];
            v = fminf(v, zsq_s[rbase + 0] - 2.f * c[0]);
            v = fminf(v, zsq_s[rbase + 1] - 2.f * c[1]);
            v = fminf(v, zsq_s[rbase + 2] - 2.f * c[2]);
            v = fminf(v, zsq_s[rbase + 3] - 2.f * c[3]);
        }
        v = fminf(v, __shfl_xor(v, 16, 64));
        v = fminf(v, __shfl_xor(v, 32, 64));
        if (q == 0) colmin[wm][wn * 64 + an * 16 + lrow] = v;
    }
    __syncthreads();
    if (t < BN) {
        const float m = fminf(colmin[0][t], colmin[1][t]);
        atomicMin(&min_enc[bx * BN + t], enc_f32(m));
    }

    // Fused finalize: last block to finish reduces min_enc -> mean -> out.
    __threadfence();
    if (t == 0) {
        unsigned old = __hip_atomic_fetch_add(&ctrl[0], 1u, __ATOMIC_ACQ_REL,
                                              __HIP_MEMORY_SCOPE_AGENT);
        last_flag = (old == (unsigned)(GRID_GEMM - 1));
    }
    __syncthreads();
    if (last_flag) {
        __threadfence();  // acquire
        float s = 0.f;
        #pragma unroll
        for (int i = 0; i < M_CODES / 256; i++) {
            const int j = i * 256 + t;
            unsigned enc = __hip_atomic_load(&min_enc[j], __ATOMIC_RELAXED,
                                             __HIP_MEMORY_SCOPE_AGENT);
            s += dec_f32(enc);
        }
        #pragma unroll
        for (int off = 1; off < 64; off <<= 1) s += __shfl_xor(s, off, 64);
        if (lane == 0) red[w] = s;
        __syncthreads();
        if (t == 0) {
            unsigned eb_bits = __hip_atomic_load(&ctrl[2], __ATOMIC_RELAXED,
                                                 __HIP_MEMORY_SCOPE_AGENT);
            float esq_total = __uint_as_float(eb_bits);
            out[0] = (red[0] + red[1] + red[2] + red[3] + esq_total)
                     * (1.f / M_CODES);
        }
    }
}

extern "C" void kernel_launch(void* const* d_in, const int* in_sizes, int n_in,
                              void* d_out, int out_size, void* d_ws, size_t ws_size,
                              hipStream_t stream) {
    (void)in_sizes; (void)n_in; (void)out_size; (void)ws_size;
    const float* z = (const float*)d_in[0];
    const float* e = (const float*)d_in[1];
    char* ws = (char*)d_ws;
    unsigned short* zb = (unsigned short*)ws;                            // 8 MB
    unsigned short* eb = (unsigned short*)(ws + ((size_t)8 << 20));      // 8 MB
    float* zsq = (float*)(ws + ((size_t)16 << 20));                      // 16 KB
    unsigned* min_enc = (unsigned*)(ws + ((size_t)16 << 20) + 16384);    // 16 KB
    unsigned* ctrl = (unsigned*)(ws + ((size_t)16 << 20) + 32768);       // 16 B

    prep_kernel<<<dim3(1024), dim3(256), 0, stream>>>(
        z, e, zb, eb, zsq, min_enc, ctrl);
    gemm_min_kernel<<<dim3(M_CODES / BN, N_PTS / BM), dim3(256), 0, stream>>>(
        zb, eb, zsq, min_enc, ctrl, (float*)d_out);
}

// Round 5
// 121.822 us; speedup vs baseline: 3.8333x; 2.0140x over previous
//
#include <hip/hip_runtime.h>
#include <hip/hip_bf16.h>
#include <stdint.h>

#define N_PTS   4096
#define M_CODES 4096
#define ZDIM    1024
#define BM 128
#define BN 128
#define BK 32

typedef __attribute__((ext_vector_type(8))) short bf16x8;
typedef __attribute__((ext_vector_type(4))) float f32x4;

__device__ __forceinline__ unsigned short f2bf(float f) {
    __hip_bfloat16 h = __float2bfloat16(f);
    return *reinterpret_cast<unsigned short*>(&h);
}

// order-preserving float -> uint map (monotone): enables atomicMin on uint
__device__ __forceinline__ unsigned enc_f32(float f) {
    unsigned u = __float_as_uint(f);
    return (u & 0x80000000u) ? ~u : (u | 0x80000000u);
}
__device__ __forceinline__ float dec_f32(unsigned e) {
    unsigned u = (e & 0x80000000u) ? (e ^ 0x80000000u) : ~e;
    return __uint_as_float(u);
}

// ---------------------------------------------------------------------------
// prep: fp32 -> bf16 convert + row sum-of-squares, high-ILP.
// 1024 blocks x 256 threads; 8 rows/block (2 rows/wave), 8 float4 loads/lane
// in flight, no LDS, no __syncthreads, no atomics (esq stored per-row).
// Blocks 0..15 also init min_enc. NO device-scope fences (R4 lesson: fences
// thrash per-XCD L2s).
// ---------------------------------------------------------------------------
__global__ __launch_bounds__(256) void prep_kernel(
    const float* __restrict__ z, const float* __restrict__ e,
    unsigned short* __restrict__ zb, unsigned short* __restrict__ eb,
    float* __restrict__ zsq, float* __restrict__ esq,
    unsigned* __restrict__ min_enc) {
    const int t = threadIdx.x;
    const int b = blockIdx.x;
    if (b < 16) min_enc[b * 256 + t] = 0xFFFFFFFFu;  // encodes "+huge"

    const int w = t >> 6, lane = t & 63;
    const bool is_z = b < 512;  // block-uniform: first 512 blocks do z, rest e
    #pragma unroll
    for (int r2 = 0; r2 < 2; r2++) {
        const int rr = (b & 511) * 8 + w * 2 + r2;  // row within z or e
        const float4* s4 =
            reinterpret_cast<const float4*>((is_z ? z : e) + (size_t)rr * ZDIM);
        ushort4* d4 =
            reinterpret_cast<ushort4*>((is_z ? zb : eb) + (size_t)rr * ZDIM);
        float4 v0 = s4[lane], v1 = s4[64 + lane], v2 = s4[128 + lane],
               v3 = s4[192 + lane];
        ushort4 o0, o1, o2, o3;
        o0.x = f2bf(v0.x); o0.y = f2bf(v0.y); o0.z = f2bf(v0.z); o0.w = f2bf(v0.w);
        o1.x = f2bf(v1.x); o1.y = f2bf(v1.y); o1.z = f2bf(v1.z); o1.w = f2bf(v1.w);
        o2.x = f2bf(v2.x); o2.y = f2bf(v2.y); o2.z = f2bf(v2.z); o2.w = f2bf(v2.w);
        o3.x = f2bf(v3.x); o3.y = f2bf(v3.y); o3.z = f2bf(v3.z); o3.w = f2bf(v3.w);
        d4[lane] = o0; d4[64 + lane] = o1; d4[128 + lane] = o2; d4[192 + lane] = o3;
        float s = v0.x * v0.x + v0.y * v0.y + v0.z * v0.z + v0.w * v0.w
                + v1.x * v1.x + v1.y * v1.y + v1.z * v1.z + v1.w * v1.w
                + v2.x * v2.x + v2.y * v2.y + v2.z * v2.z + v2.w * v2.w
                + v3.x * v3.x + v3.y * v3.y + v3.z * v3.z + v3.w * v3.w;
        #pragma unroll
        for (int off = 1; off < 64; off <<= 1) s += __shfl_xor(s, off, 64);
        if (lane == 0) {
            if (is_z) zsq[rr] = s; else esq[rr] = s;
        }
    }
}

// ---------------------------------------------------------------------------
// gemm_min: R1-verbatim. 128x128x32 bf16 MFMA tile, lane-contiguous
// global_load_lds staging, fused column-min epilogue (per-wave atomicMin,
// 256/block). NO fences, NO done-counter (R4 lesson).
// grid = (32, 32), 256 threads = 4 waves (2x2 of 64x64).
// ---------------------------------------------------------------------------
__global__ __launch_bounds__(256) void gemm_min_kernel(
    const unsigned short* __restrict__ zb, const unsigned short* __restrict__ eb,
    const float* __restrict__ zsq, unsigned* __restrict__ min_enc) {
    __shared__ __align__(16) unsigned short As[BM * BK];  // 8 KB
    __shared__ __align__(16) unsigned short Bs[BN * BK];  // 8 KB
    __shared__ float zsq_s[BM];

    const int t = threadIdx.x;
    const int bx = blockIdx.x;  // code (col) block
    const int by = blockIdx.y;  // point (row) block
    const int lane = t & 63;
    const int w = t >> 6;
    const int wm = w >> 1, wn = w & 1;
    const int lrow = lane & 15;
    const int q = lane >> 4;

    if (t < BM) zsq_s[t] = zsq[by * BM + t];

    f32x4 acc[4][4];
    #pragma unroll
    for (int i = 0; i < 4; i++)
        #pragma unroll
        for (int j = 0; j < 4; j++) acc[i][j] = (f32x4){0.f, 0.f, 0.f, 0.f};

    // staging geometry: thread t covers bytes [t*16, t*16+16) of the 8 KB tile
    // (instr 0), and the same +4096 B (instr 1). Tile row = 64 B.
    const int row0 = (t * 16) >> 6;         // 0..63
    const int kel0 = ((t * 16) & 63) >> 1;  // k-element offset 0/8/16/24
    const int lds_b0 = w * 512;             // wave-uniform LDS base (elements)
    const size_t a_base = (size_t)(by * BM) * ZDIM;
    const size_t b_base = (size_t)(bx * BN) * ZDIM;

    for (int k0 = 0; k0 < ZDIM; k0 += BK) {
        const unsigned short* ga0 = zb + a_base + (size_t)row0 * ZDIM + k0 + kel0;
        const unsigned short* gb0 = eb + b_base + (size_t)row0 * ZDIM + k0 + kel0;
        __builtin_amdgcn_global_load_lds(
            (const __attribute__((address_space(1))) void*)ga0,
            (__attribute__((address_space(3))) void*)(As + lds_b0), 16, 0, 0);
        __builtin_amdgcn_global_load_lds(
            (const __attribute__((address_space(1))) void*)(ga0 + (size_t)64 * ZDIM),
            (__attribute__((address_space(3))) void*)(As + 2048 + lds_b0), 16, 0, 0);
        __builtin_amdgcn_global_load_lds(
            (const __attribute__((address_space(1))) void*)gb0,
            (__attribute__((address_space(3))) void*)(Bs + lds_b0), 16, 0, 0);
        __builtin_amdgcn_global_load_lds(
            (const __attribute__((address_space(1))) void*)(gb0 + (size_t)64 * ZDIM),
            (__attribute__((address_space(3))) void*)(Bs + 2048 + lds_b0), 16, 0, 0);
        __syncthreads();

        bf16x8 a[4], bb[4];
        #pragma unroll
        for (int am = 0; am < 4; am++)
            a[am] = *(const bf16x8*)(As + (wm * 64 + am * 16 + lrow) * BK + q * 8);
        #pragma unroll
        for (int an = 0; an < 4; an++)
            bb[an] = *(const bf16x8*)(Bs + (wn * 64 + an * 16 + lrow) * BK + q * 8);
        #pragma unroll
        for (int am = 0; am < 4; am++)
            #pragma unroll
            for (int an = 0; an < 4; an++)
                acc[am][an] = __builtin_amdgcn_mfma_f32_16x16x32_bf16(
                    a[am], bb[an], acc[am][an], 0, 0, 0);
        __syncthreads();
    }

    // Epilogue: per-lane min over (am, reg), cross-lane over q-groups,
    // then device atomicMin per column. C/D layout: row = q*4+r, col = lrow.
    #pragma unroll
    for (int an = 0; an < 4; an++) {
        float v = 3.4e38f;
        #pragma unroll
        for (int am = 0; am < 4; am++) {
            const int rbase = wm * 64 + am * 16 + q * 4;
            f32x4 c = acc[am][an];
            v = fminf(v, zsq_s[rbase + 0] - 2.f * c[0]);
            v = fminf(v, zsq_s[rbase + 1] - 2.f * c[1]);
            v = fminf(v, zsq_s[rbase + 2] - 2.f * c[2]);
            v = fminf(v, zsq_s[rbase + 3] - 2.f * c[3]);
        }
        v = fminf(v, __shfl_xor(v, 16, 64));
        v = fminf(v, __shfl_xor(v, 32, 64));
        if (q == 0) {
            const int col = bx * BN + wn * 64 + an * 16 + lrow;
            atomicMin(&min_enc[col], enc_f32(v));
        }
    }
}

// ---------------------------------------------------------------------------
// finalize: mean_j (dec(min_enc[j]) + esq[j]) -> single fp32 scalar.
// ---------------------------------------------------------------------------
__global__ __launch_bounds__(256) void finalize_kernel(
    const unsigned* __restrict__ min_enc, const float* __restrict__ esq,
    float* __restrict__ out) {
    const int t = threadIdx.x;
    float s = 0.f;
    #pragma unroll
    for (int i = 0; i < M_CODES / 256; i++) {
        const int j = i * 256 + t;
        s += dec_f32(min_enc[j]) + esq[j];
    }
    #pragma unroll
    for (int off = 1; off < 64; off <<= 1) s += __shfl_xor(s, off, 64);
    __shared__ float red[4];
    if ((t & 63) == 0) red[t >> 6] = s;
    __syncthreads();
    if (t == 0) out[0] = (red[0] + red[1] + red[2] + red[3]) * (1.f / M_CODES);
}

extern "C" void kernel_launch(void* const* d_in, const int* in_sizes, int n_in,
                              void* d_out, int out_size, void* d_ws, size_t ws_size,
                              hipStream_t stream) {
    (void)in_sizes; (void)n_in; (void)out_size; (void)ws_size;
    const float* z = (const float*)d_in[0];
    const float* e = (const float*)d_in[1];
    char* ws = (char*)d_ws;
    unsigned short* zb = (unsigned short*)ws;                            // 8 MB
    unsigned short* eb = (unsigned short*)(ws + ((size_t)8 << 20));      // 8 MB
    float* zsq = (float*)(ws + ((size_t)16 << 20));                      // 16 KB
    float* esq = (float*)(ws + ((size_t)16 << 20) + 16384);              // 16 KB
    unsigned* min_enc = (unsigned*)(ws + ((size_t)16 << 20) + 32768);    // 16 KB

    prep_kernel<<<dim3(1024), dim3(256), 0, stream>>>(
        z, e, zb, eb, zsq, esq, min_enc);
    gemm_min_kernel<<<dim3(M_CODES / BN, N_PTS / BM), dim3(256), 0, stream>>>(
        zb, eb, zsq, min_enc);
    finalize_kernel<<<dim3(1), dim3(256), 0, stream>>>(min_enc, esq, (float*)d_out);
}

// Round 6
// 117.129 us; speedup vs baseline: 3.9869x; 1.0401x over previous
//
#include <hip/hip_runtime.h>
#include <hip/hip_bf16.h>
#include <stdint.h>

#define N_PTS   4096
#define M_CODES 4096
#define ZDIM    1024
#define BM 128
#define BN 128
#define BK 32    // per slice; 2 slices staged per barrier pair

typedef __attribute__((ext_vector_type(8))) short bf16x8;
typedef __attribute__((ext_vector_type(4))) float f32x4;

__device__ __forceinline__ unsigned short f2bf(float f) {
    __hip_bfloat16 h = __float2bfloat16(f);
    return *reinterpret_cast<unsigned short*>(&h);
}

// order-preserving float -> uint map (monotone): enables atomicMin on uint
__device__ __forceinline__ unsigned enc_f32(float f) {
    unsigned u = __float_as_uint(f);
    return (u & 0x80000000u) ? ~u : (u | 0x80000000u);
}
__device__ __forceinline__ float dec_f32(unsigned e) {
    unsigned u = (e & 0x80000000u) ? (e ^ 0x80000000u) : ~e;
    return __uint_as_float(u);
}

// ---------------------------------------------------------------------------
// prep: fp32 -> bf16 convert + row sum-of-squares (R5-proven, unchanged).
// 1024 blocks x 256 threads; 8 rows/block, no LDS/syncthreads/atomics/fences.
// ---------------------------------------------------------------------------
__global__ __launch_bounds__(256) void prep_kernel(
    const float* __restrict__ z, const float* __restrict__ e,
    unsigned short* __restrict__ zb, unsigned short* __restrict__ eb,
    float* __restrict__ zsq, float* __restrict__ esq,
    unsigned* __restrict__ min_enc) {
    const int t = threadIdx.x;
    const int b = blockIdx.x;
    if (b < 16) min_enc[b * 256 + t] = 0xFFFFFFFFu;  // encodes "+huge"

    const int w = t >> 6, lane = t & 63;
    const bool is_z = b < 512;
    #pragma unroll
    for (int r2 = 0; r2 < 2; r2++) {
        const int rr = (b & 511) * 8 + w * 2 + r2;
        const float4* s4 =
            reinterpret_cast<const float4*>((is_z ? z : e) + (size_t)rr * ZDIM);
        ushort4* d4 =
            reinterpret_cast<ushort4*>((is_z ? zb : eb) + (size_t)rr * ZDIM);
        float4 v0 = s4[lane], v1 = s4[64 + lane], v2 = s4[128 + lane],
               v3 = s4[192 + lane];
        ushort4 o0, o1, o2, o3;
        o0.x = f2bf(v0.x); o0.y = f2bf(v0.y); o0.z = f2bf(v0.z); o0.w = f2bf(v0.w);
        o1.x = f2bf(v1.x); o1.y = f2bf(v1.y); o1.z = f2bf(v1.z); o1.w = f2bf(v1.w);
        o2.x = f2bf(v2.x); o2.y = f2bf(v2.y); o2.z = f2bf(v2.z); o2.w = f2bf(v2.w);
        o3.x = f2bf(v3.x); o3.y = f2bf(v3.y); o3.z = f2bf(v3.z); o3.w = f2bf(v3.w);
        d4[lane] = o0; d4[64 + lane] = o1; d4[128 + lane] = o2; d4[192 + lane] = o3;
        float s = v0.x * v0.x + v0.y * v0.y + v0.z * v0.z + v0.w * v0.w
                + v1.x * v1.x + v1.y * v1.y + v1.z * v1.z + v1.w * v1.w
                + v2.x * v2.x + v2.y * v2.y + v2.z * v2.z + v2.w * v2.w
                + v3.x * v3.x + v3.y * v3.y + v3.z * v3.z + v3.w * v3.w;
        #pragma unroll
        for (int off = 1; off < 64; off <<= 1) s += __shfl_xor(s, off, 64);
        if (lane == 0) {
            if (is_z) zsq[rr] = s; else esq[rr] = s;
        }
    }
}

// ---------------------------------------------------------------------------
// gemm_min: 128x128 tile; per barrier pair, TWO BK=32 slices are staged
// (8 global_load_lds, 64 k-elements) then 2x(8 ds_read_b128 + 16 MFMA).
// Halves the vmcnt(0)+s_barrier drain count vs R5 (32 MFMA per barrier).
// Lane-contiguous staging (R2 lesson: never swizzle global sources).
// No fences / no done-counter (R4 lesson). grid (32,32), 4 waves.
// ---------------------------------------------------------------------------
__global__ __launch_bounds__(256) void gemm_min_kernel(
    const unsigned short* __restrict__ zb, const unsigned short* __restrict__ eb,
    const float* __restrict__ zsq, unsigned* __restrict__ min_enc) {
    __shared__ __align__(16) unsigned short As[2 * BM * BK];  // 16 KB
    __shared__ __align__(16) unsigned short Bs[2 * BN * BK];  // 16 KB
    __shared__ float zsq_s[BM];

    const int t = threadIdx.x;
    const int bx = blockIdx.x;  // code (col) block
    const int by = blockIdx.y;  // point (row) block
    const int lane = t & 63;
    const int w = t >> 6;
    const int wm = w >> 1, wn = w & 1;
    const int lrow = lane & 15;
    const int q = lane >> 4;

    if (t < BM) zsq_s[t] = zsq[by * BM + t];

    f32x4 acc[4][4];
    #pragma unroll
    for (int i = 0; i < 4; i++)
        #pragma unroll
        for (int j = 0; j < 4; j++) acc[i][j] = (f32x4){0.f, 0.f, 0.f, 0.f};

    // staging geometry (per slice, R1-proven): thread t covers bytes
    // [t*16, t*16+16) of the 8 KB slice (instr 0) and +4096 B (instr 1).
    const int row0 = (t * 16) >> 6;         // 0..63
    const int kel0 = ((t * 16) & 63) >> 1;  // k-element offset 0/8/16/24
    const int lds_b0 = w * 512;             // wave-uniform LDS base (elements)
    const size_t a_base = (size_t)(by * BM) * ZDIM;
    const size_t b_base = (size_t)(bx * BN) * ZDIM;

    for (int k0 = 0; k0 < ZDIM; k0 += 2 * BK) {
        #pragma unroll
        for (int s = 0; s < 2; s++) {
            const unsigned short* ga0 =
                zb + a_base + (size_t)row0 * ZDIM + k0 + s * BK + kel0;
            const unsigned short* gb0 =
                eb + b_base + (size_t)row0 * ZDIM + k0 + s * BK + kel0;
            __builtin_amdgcn_global_load_lds(
                (const __attribute__((address_space(1))) void*)ga0,
                (__attribute__((address_space(3))) void*)(As + s * 4096 + lds_b0),
                16, 0, 0);
            __builtin_amdgcn_global_load_lds(
                (const __attribute__((address_space(1))) void*)(ga0 + (size_t)64 * ZDIM),
                (__attribute__((address_space(3))) void*)(As + s * 4096 + 2048 + lds_b0),
                16, 0, 0);
            __builtin_amdgcn_global_load_lds(
                (const __attribute__((address_space(1))) void*)gb0,
                (__attribute__((address_space(3))) void*)(Bs + s * 4096 + lds_b0),
                16, 0, 0);
            __builtin_amdgcn_global_load_lds(
                (const __attribute__((address_space(1))) void*)(gb0 + (size_t)64 * ZDIM),
                (__attribute__((address_space(3))) void*)(Bs + s * 4096 + 2048 + lds_b0),
                16, 0, 0);
        }
        __syncthreads();

        #pragma unroll
        for (int s = 0; s < 2; s++) {
            bf16x8 a[4], bb[4];
            #pragma unroll
            for (int am = 0; am < 4; am++)
                a[am] = *(const bf16x8*)(As + s * 4096 +
                                         (wm * 64 + am * 16 + lrow) * BK + q * 8);
            #pragma unroll
            for (int an = 0; an < 4; an++)
                bb[an] = *(const bf16x8*)(Bs + s * 4096 +
                                          (wn * 64 + an * 16 + lrow) * BK + q * 8);
            #pragma unroll
            for (int am = 0; am < 4; am++)
                #pragma unroll
                for (int an = 0; an < 4; an++)
                    acc[am][an] = __builtin_amdgcn_mfma_f32_16x16x32_bf16(
                        a[am], bb[an], acc[am][an], 0, 0, 0);
        }
        __syncthreads();
    }

    // Epilogue (R5-proven). C/D layout: row = q*4+r, col = lrow.
    #pragma unroll
    for (int an = 0; an < 4; an++) {
        float v = 3.4e38f;
        #pragma unroll
        for (int am = 0; am < 4; am++) {
            const int rbase = wm * 64 + am * 16 + q * 4;
            f32x4 c = acc[am][an];
            v = fminf(v, zsq_s[rbase + 0] - 2.f * c[0]);
            v = fminf(v, zsq_s[rbase + 1] - 2.f * c[1]);
            v = fminf(v, zsq_s[rbase + 2] - 2.f * c[2]);
            v = fminf(v, zsq_s[rbase + 3] - 2.f * c[3]);
        }
        v = fminf(v, __shfl_xor(v, 16, 64));
        v = fminf(v, __shfl_xor(v, 32, 64));
        if (q == 0) {
            const int col = bx * BN + wn * 64 + an * 16 + lrow;
            atomicMin(&min_enc[col], enc_f32(v));
        }
    }
}

// ---------------------------------------------------------------------------
// finalize: mean_j (dec(min_enc[j]) + esq[j]) -> single fp32 scalar.
// ---------------------------------------------------------------------------
__global__ __launch_bounds__(256) void finalize_kernel(
    const unsigned* __restrict__ min_enc, const float* __restrict__ esq,
    float* __restrict__ out) {
    const int t = threadIdx.x;
    float s = 0.f;
    #pragma unroll
    for (int i = 0; i < M_CODES / 256; i++) {
        const int j = i * 256 + t;
        s += dec_f32(min_enc[j]) + esq[j];
    }
    #pragma unroll
    for (int off = 1; off < 64; off <<= 1) s += __shfl_xor(s, off, 64);
    __shared__ float red[4];
    if ((t & 63) == 0) red[t >> 6] = s;
    __syncthreads();
    if (t == 0) out[0] = (red[0] + red[1] + red[2] + red[3]) * (1.f / M_CODES);
}

extern "C" void kernel_launch(void* const* d_in, const int* in_sizes, int n_in,
                              void* d_out, int out_size, void* d_ws, size_t ws_size,
                              hipStream_t stream) {
    (void)in_sizes; (void)n_in; (void)out_size; (void)ws_size;
    const float* z = (const float*)d_in[0];
    const float* e = (const float*)d_in[1];
    char* ws = (char*)d_ws;
    unsigned short* zb = (unsigned short*)ws;                            // 8 MB
    unsigned short* eb = (unsigned short*)(ws + ((size_t)8 << 20));      // 8 MB
    float* zsq = (float*)(ws + ((size_t)16 << 20));                      // 16 KB
    float* esq = (float*)(ws + ((size_t)16 << 20) + 16384);              // 16 KB
    unsigned* min_enc = (unsigned*)(ws + ((size_t)16 << 20) + 32768);    // 16 KB

    prep_kernel<<<dim3(1024), dim3(256), 0, stream>>>(
        z, e, zb, eb, zsq, esq, min_enc);
    gemm_min_kernel<<<dim3(M_CODES / BN, N_PTS / BM), dim3(256), 0, stream>>>(
        zb, eb, zsq, min_enc);
    finalize_kernel<<<dim3(1), dim3(256), 0, stream>>>(min_enc, esq, (float*)d_out);
}